// Round 10
// baseline (268.646 us; speedup 1.0000x reference)
//
#include <hip/hip_runtime.h>

// SpatialGridProjector: out[b,q,j,i] = sum_k trilinear(density[b], P(i,j,k))
// X(k) = Ax + k*R20, Y(k) = Ay + k*R21, Z(k) = Az + k*R22  (voxel coords)
// grid_sample(align_corners=True, zero padding).
//
// R9: revert to R6 mapping (wave = 64x1 pixel row; best measured footprint;
// R8's 16x16 tiles regressed: occ 47->30%, time 129->152 despite FETCH down).
// Changes vs R6:
//  - interior pipeline 4 -> 6 stages (24 outstanding 16B loads/thread),
//    VGPR kept <=64 via __launch_bounds__(128,8) to hold 8 waves/SIMD.
//  - 4096 blocks x 128 threads (one j-row per block): halves tail-drain
//    quantum; every pixel still in exactly ONE block (no R7 sheet doubling).

#define LSZ 128
#define PACKED_BYTES ((size_t)4 * 128 * 128 * 128 * 8)  // 64 MiB

typedef unsigned int u4v __attribute__((ext_vector_type(4), aligned(8)));

__device__ __forceinline__ float bl(unsigned int d) {
    return __uint_as_float(d << 16);
}
__device__ __forceinline__ float bh(unsigned int d) {
    return __uint_as_float(d & 0xffff0000u);
}
__device__ __forceinline__ unsigned int pk2(float lo, float hi) {
    unsigned int ul = __float_as_uint(lo), uh = __float_as_uint(hi);
    ul = (ul + 0x7fffu + ((ul >> 16) & 1u)) >> 16;   // RNE bf16
    uh = (uh + 0x7fffu + ((uh >> 16) & 1u)) >> 16;
    return ul | (uh << 16);
}

// ---------------- pack kernel: f32 volume -> corner-packed bf16 -------------
// entry (z,y,x): dword0 = bf16{ v(z,y,x), v(z,y+1,x) }
//                dword1 = bf16{ v(z+1,y,x), v(z+1,y+1,x) }
__global__ __launch_bounds__(256) void pack_kernel(
    const float* __restrict__ density, uint2* __restrict__ packed)
{
    const int xcd = blockIdx.x & 7;
    const int g   = blockIdx.x >> 3;          // 0..1023
    const int b   = g >> 8;                   // 0..3
    const int rem = g & 255;
    const int zl  = rem >> 4;                 // 0..15
    const int yo  = rem & 15;                 // 0..15
    const int z   = (xcd << 4) + zl;          // 0..127
    const int y   = (yo << 3) + (threadIdx.x >> 5);
    const int xq  = (threadIdx.x & 31) << 2;

    const float* __restrict__ v = density + ((size_t)b << 21);
    const int y1 = min(y + 1, 127), z1 = min(z + 1, 127);
    const float4 a0 = *(const float4*)(v + (z  << 14) + (y  << 7) + xq);
    const float4 a1 = *(const float4*)(v + (z  << 14) + (y1 << 7) + xq);
    const float4 c0 = *(const float4*)(v + (z1 << 14) + (y  << 7) + xq);
    const float4 c1 = *(const float4*)(v + (z1 << 14) + (y1 << 7) + xq);
    uint4 o0, o1;
    o0.x = pk2(a0.x, a1.x); o0.y = pk2(c0.x, c1.x);
    o0.z = pk2(a0.y, a1.y); o0.w = pk2(c0.y, c1.y);
    o1.x = pk2(a0.z, a1.z); o1.y = pk2(c0.z, c1.z);
    o1.z = pk2(a0.w, a1.w); o1.w = pk2(c0.w, c1.w);
    uint4* dst = (uint4*)(packed + ((size_t)b << 21) + (z << 14) + (y << 7) + xq);
    dst[0] = o0; dst[1] = o1;
}

// ---------------- interior fast path (all corners valid) --------------------
#define FPREPI(S, kk) do {                                                    \
    const float kf_ = (float)min((kk), d);                                    \
    const float X_ = fmaf(kf_, R20, Ax);                                      \
    const float Y_ = fmaf(kf_, R21, Ay);                                      \
    const float Z_ = fmaf(kf_, R22, Az);                                      \
    const int ix_ = (int)X_;                                                  \
    const int iy_ = (int)Y_;                                                  \
    const int iz_ = (int)Z_;                                                  \
    fx##S = X_ - (float)ix_;                                                  \
    fy##S = Y_ - (float)iy_;                                                  \
    fz##S = Z_ - (float)iz_;                                                  \
    u##S = *(const u4v*)(vol2 + ((iz_ << 14) + (iy_ << 7) + ix_));            \
} while (0)

#define FCONSI(S) do {                                                        \
    const float gx0 = 1.0f - fx##S;                                           \
    const float gy0 = 1.0f - fy##S;                                           \
    const float gz0 = 1.0f - fz##S;                                           \
    const float c000 = bl(u##S.x), c010 = bh(u##S.x);                         \
    const float c001 = bl(u##S.y), c011 = bh(u##S.y);                         \
    const float c100 = bl(u##S.z), c110 = bh(u##S.z);                         \
    const float c101 = bl(u##S.w), c111 = bh(u##S.w);                         \
    const float s0_ = gy0   * fmaf(gx0, c000, fx##S * c100)                   \
                    + fy##S * fmaf(gx0, c010, fx##S * c110);                  \
    const float s1_ = gy0   * fmaf(gx0, c001, fx##S * c101)                   \
                    + fy##S * fmaf(gx0, c011, fx##S * c111);                  \
    acc = fmaf(gz0, s0_, fmaf(fz##S, s1_, acc));                              \
} while (0)

// ---------------- boundary safe path (clamped + per-corner selects) ---------
#define SPREP(S, kk) do {                                                     \
    const float kf_ = (float)(kk);                                            \
    const float X_ = fmaf(kf_, R20, Ax);                                      \
    const float Y_ = fmaf(kf_, R21, Ay);                                      \
    const float Z_ = fmaf(kf_, R22, Az);                                      \
    const int ix_ = (int)floorf(X_);                                          \
    const int iy_ = (int)floorf(Y_);                                          \
    const int iz_ = (int)floorf(Z_);                                          \
    const int ex_ = min(max(ix_, 0), 126);                                    \
    const int ey_ = min(max(iy_, 0), 126);                                    \
    const int ez_ = min(max(iz_, 0), 126);                                    \
    u##S = *(const u4v*)(vol2 + ((ez_ << 14) + (ey_ << 7) + ex_));            \
} while (0)

#define SCONS(S, kk) do {                                                     \
    const float kf_ = (float)(kk);                                            \
    const float X_ = fmaf(kf_, R20, Ax);                                      \
    const float Y_ = fmaf(kf_, R21, Ay);                                      \
    const float Z_ = fmaf(kf_, R22, Az);                                      \
    const float xf_ = floorf(X_), yf_ = floorf(Y_), zf_ = floorf(Z_);         \
    const int ix_ = (int)xf_, iy_ = (int)yf_, iz_ = (int)zf_;                 \
    const float fx_ = X_ - xf_, fy_ = Y_ - yf_, fz_ = Z_ - zf_;               \
    const bool vx0_ = (ix_ >= 0)  & (ix_ <= 127);                             \
    const bool vx1_ = (ix_ >= -1) & (ix_ <= 126);                             \
    const bool vy0_ = (iy_ >= 0)  & (iy_ <= 127);                             \
    const bool vy1_ = (iy_ >= -1) & (iy_ <= 126);                             \
    const bool vz0_ = (iz_ >= 0)  & (iz_ <= 127);                             \
    const bool vz1_ = (iz_ >= -1) & (iz_ <= 126);                             \
    const float gx0 = vx0_ ? (1.0f - fx_) : 0.0f;                             \
    const float gx1 = vx1_ ? fx_ : 0.0f;                                      \
    const float gy0 = vy0_ ? (1.0f - fy_) : 0.0f;                             \
    const float gy1 = vy1_ ? fy_ : 0.0f;                                      \
    const float gz0 = vz0_ ? (1.0f - fz_) : 0.0f;                             \
    const float gz1 = vz1_ ? fz_ : 0.0f;                                      \
    const bool xhi_ = (ix_ > 126), xlo_ = (ix_ < 0);                          \
    const bool yhi_ = (iy_ > 126), ylo_ = (iy_ < 0);                          \
    const bool zhi_ = (iz_ > 126), zlo_ = (iz_ < 0);                          \
    const unsigned int a0z0 = xhi_ ? u##S.z : u##S.x;                         \
    const unsigned int a0z1 = xhi_ ? u##S.w : u##S.y;                         \
    const unsigned int a1z0 = xlo_ ? u##S.x : u##S.z;                         \
    const unsigned int a1z1 = xlo_ ? u##S.y : u##S.w;                         \
    const unsigned int dA = zhi_ ? a0z1 : a0z0;                               \
    const unsigned int dB = zlo_ ? a0z0 : a0z1;                               \
    const unsigned int dC = zhi_ ? a1z1 : a1z0;                               \
    const unsigned int dD = zlo_ ? a1z0 : a1z1;                               \
    const float c000 = yhi_ ? bh(dA) : bl(dA);                                \
    const float c010 = ylo_ ? bl(dA) : bh(dA);                                \
    const float c100 = yhi_ ? bh(dC) : bl(dC);                                \
    const float c110 = ylo_ ? bl(dC) : bh(dC);                                \
    const float c001 = yhi_ ? bh(dB) : bl(dB);                                \
    const float c011 = ylo_ ? bl(dB) : bh(dB);                                \
    const float c101 = yhi_ ? bh(dD) : bl(dD);                                \
    const float c111 = ylo_ ? bl(dD) : bh(dD);                                \
    const float s0_ = gy0 * fmaf(gx0, c000, gx1 * c100)                       \
                    + gy1 * fmaf(gx0, c010, gx1 * c110);                      \
    const float s1_ = gy0 * fmaf(gx0, c001, gx1 * c101)                       \
                    + gy1 * fmaf(gx0, c011, gx1 * c111);                      \
    acc = fmaf(gz0, s0_, fmaf(gz1, s1_, acc));                                \
} while (0)

__global__ __launch_bounds__(128, 8) void proj_kernel_packed(
    const uint2* __restrict__ packed,    // (B, L, L, L) corner-packed bf16
    const float* __restrict__ rotation,  // (B, Q, 3, 3)
    float* __restrict__ out)             // (B, Q, L, L)
{
    // XCD swizzle: volume b -> XCDs {2b, 2b+1}. Block = one j-row (128 px).
    const int xcd  = blockIdx.x & 7;
    const int slot = blockIdx.x >> 3;           // 0..511
    const int b    = xcd >> 1;
    const int tile = ((xcd & 1) << 9) + slot;   // 0..1023
    const int q    = tile >> 7;                 // 0..7
    const int j    = tile & 127;
    const int bq   = (b << 3) + q;
    const int i    = threadIdx.x;

    const float* R = rotation + bq * 9;
    const float R00 = R[0], R01 = R[1], R02 = R[2];
    const float R10 = R[3], R11 = R[4], R12 = R[5];
    const float R20 = R[6], R21 = R[7], R22 = R[8];

    const float step = 2.0f / 127.0f;
    const float li = -1.0f + (float)i * step;
    const float lj = -1.0f + (float)j * step;

    const float Ax = 63.5f * (li * R00 + lj * R10 - R20 + 1.0f);
    const float Ay = 63.5f * (li * R01 + lj * R11 - R21 + 1.0f);
    const float Az = 63.5f * (li * R02 + lj * R12 - R22 + 1.0f);

    // outer interval: A + k*s in (-1, 128); interior: in [0, 126.95]
    float klo = 0.0f, khi = 127.0f;
    float klo2 = 0.0f, khi2 = 127.0f;
    bool empty = false, empty2 = false;
    {
        const float a_[3] = {Ax, Ay, Az};
        const float s_[3] = {R20, R21, R22};
        #pragma unroll
        for (int m = 0; m < 3; ++m) {
            if (fabsf(s_[m]) > 1e-6f) {
                const float r = 1.0f / s_[m];
                const float t0 = (-1.0f   - a_[m]) * r;
                const float t1 = (128.0f  - a_[m]) * r;
                klo = fmaxf(klo, fminf(t0, t1));
                khi = fminf(khi, fmaxf(t0, t1));
                const float w0 = (0.0f    - a_[m]) * r;
                const float w1 = (126.95f - a_[m]) * r;
                klo2 = fmaxf(klo2, fminf(w0, w1));
                khi2 = fminf(khi2, fmaxf(w0, w1));
            } else {
                if (a_[m] <= -1.0f   || a_[m] >= 128.0f)   empty  = true;
                if (a_[m] <  0.001f  || a_[m] >  126.94f)  empty2 = true;
            }
        }
    }
    int a   = (int)ceilf(klo - 1e-3f);
    int bnd = (int)floorf(khi + 1e-3f);
    if (a < 0) a = 0;
    if (bnd > 127) bnd = 127;
    if (empty) bnd = a - 1;

    int c = (int)ceilf(klo2 + 0.05f);
    int d = (int)floorf(khi2 - 0.05f);
    if (c < a) c = a;
    if (d > bnd) d = bnd;
    if (empty2 || d < c) { c = bnd + 1; d = bnd; }

    const uint2* __restrict__ vol2 = packed + ((size_t)b << 21);

    float acc = 0.0f;
    u4v uA, uB, uC, uD, uE, uF;
    float fxA, fyA, fzA, fxB, fyB, fzB, fxC, fyC, fzC;
    float fxD, fyD, fzD, fxE, fyE, fzE, fxF, fyF, fzF;

    // ---- boundary head: [a, c-1] ----
    {
        int k = a;
        const int e = c - 1;
        if (k <= e) {
            SPREP(A, k);
            while (k <= e) {
                const int kn = k + 1;
                const bool hasB = (kn <= e);
                if (hasB) SPREP(B, kn);
                SCONS(A, k);
                if (hasB) SCONS(B, kn);
                k += 2;
                if (k <= e) SPREP(A, k);
            }
        }
    }

    // ---- interior: [c, d], 6-stage fast pipeline (no clamps/selects) ----
    {
        int n = d - c + 1;
        int k = c;
        if (n > 0) {
            FPREPI(A, k);     FPREPI(B, k + 1); FPREPI(C, k + 2);
            FPREPI(D, k + 3); FPREPI(E, k + 4);
            while (n > 0) {
                FPREPI(F, k + 5);
                FCONSI(A);
                FPREPI(A, k + 6);
                if (n > 1) FCONSI(B);
                FPREPI(B, k + 7);
                if (n > 2) FCONSI(C);
                FPREPI(C, k + 8);
                if (n > 3) FCONSI(D);
                FPREPI(D, k + 9);
                if (n > 4) FCONSI(E);
                FPREPI(E, k + 10);
                if (n > 5) FCONSI(F);
                k += 6; n -= 6;
            }
        }
    }

    // ---- boundary tail: [d+1, bnd] ----
    {
        int k = d + 1;
        const int e = bnd;
        if (k <= e) {
            SPREP(A, k);
            while (k <= e) {
                const int kn = k + 1;
                const bool hasB = (kn <= e);
                if (hasB) SPREP(B, kn);
                SCONS(A, k);
                if (hasB) SCONS(B, kn);
                k += 2;
                if (k <= e) SPREP(A, k);
            }
        }
    }

    out[(bq << 14) + (j << 7) + i] = acc;
}

// ---------------- fallback (f32 direct) if ws too small ---------------------
__global__ __launch_bounds__(256) void proj_kernel_fallback(
    const float* __restrict__ density,
    const float* __restrict__ rotation,
    float* __restrict__ out)
{
    const int xcd  = blockIdx.x & 7;
    const int slot = blockIdx.x >> 3;
    const int b    = xcd >> 1;
    const int tile = ((xcd & 1) << 8) + slot;
    const int q    = tile >> 6;
    const int blk  = tile & 63;
    const int bq   = (b << 3) + q;

    const int p = (blk << 8) + threadIdx.x;
    const int i = p & (LSZ - 1);
    const int j = p >> 7;

    const float* R = rotation + bq * 9;
    const float R00 = R[0], R01 = R[1], R02 = R[2];
    const float R10 = R[3], R11 = R[4], R12 = R[5];
    const float R20 = R[6], R21 = R[7], R22 = R[8];

    const float step = 2.0f / 127.0f;
    const float li = -1.0f + (float)i * step;
    const float lj = -1.0f + (float)j * step;

    const float Ax = 63.5f * (li * R00 + lj * R10 - R20 + 1.0f);
    const float Ay = 63.5f * (li * R01 + lj * R11 - R21 + 1.0f);
    const float Az = 63.5f * (li * R02 + lj * R12 - R22 + 1.0f);

    float klo = 0.0f, khi = 127.0f;
    bool empty = false;
    {
        const float a_[3] = {Ax, Ay, Az};
        const float s_[3] = {R20, R21, R22};
        #pragma unroll
        for (int m = 0; m < 3; ++m) {
            if (fabsf(s_[m]) > 1e-6f) {
                const float t0 = (-1.0f  - a_[m]) / s_[m];
                const float t1 = (128.0f - a_[m]) / s_[m];
                klo = fmaxf(klo, fminf(t0, t1));
                khi = fminf(khi, fmaxf(t0, t1));
            } else if (a_[m] <= -1.0f || a_[m] >= 128.0f) {
                empty = true;
            }
        }
    }
    int k_start = (int)ceilf(klo - 1e-3f);
    int k_end   = (int)floorf(khi + 1e-3f);
    if (k_start < 0) k_start = 0;
    if (k_end > 127) k_end = 127;
    if (empty) k_end = k_start - 1;

    const float* __restrict__ vol = density + (size_t)b * (LSZ * LSZ * LSZ);

    float acc = 0.0f;
    for (int k = k_start; k <= k_end; ++k) {
        const float kf = (float)k;
        const float X = fmaf(kf, R20, Ax);
        const float Y = fmaf(kf, R21, Ay);
        const float Z = fmaf(kf, R22, Az);
        const float xf = floorf(X), yf = floorf(Y), zf = floorf(Z);
        const int ix = (int)xf, iy = (int)yf, iz = (int)zf;
        const float fx = X - xf, fy = Y - yf, fz = Z - zf;
        const bool vx0 = (ix >= 0)  & (ix <= 127);
        const bool vx1 = (ix >= -1) & (ix <= 126);
        const bool vy0 = (iy >= 0)  & (iy <= 127);
        const bool vy1 = (iy >= -1) & (iy <= 126);
        const bool vz0 = (iz >= 0)  & (iz <= 127);
        const bool vz1 = (iz >= -1) & (iz <= 126);
        const int cx0 = min(max(ix, 0), 127);
        const int cx1 = min(max(ix + 1, 0), 127);
        const int cy0 = min(max(iy, 0), 127);
        const int cy1 = min(max(iy + 1, 0), 127);
        const int cz0 = min(max(iz, 0), 127);
        const int cz1 = min(max(iz + 1, 0), 127);
        const float gx0 = vx0 ? (1.0f - fx) : 0.0f;
        const float gx1 = vx1 ? fx : 0.0f;
        const float gy0 = vy0 ? (1.0f - fy) : 0.0f;
        const float gy1 = vy1 ? fy : 0.0f;
        const float gz0 = vz0 ? (1.0f - fz) : 0.0f;
        const float gz1 = vz1 ? fz : 0.0f;
        const int z0o = cz0 << 14, z1o = cz1 << 14;
        const int y0o = cy0 << 7,  y1o = cy1 << 7;
        const float v000 = vol[z0o + y0o + cx0];
        const float v100 = vol[z0o + y0o + cx1];
        const float v010 = vol[z0o + y1o + cx0];
        const float v110 = vol[z0o + y1o + cx1];
        const float v001 = vol[z1o + y0o + cx0];
        const float v101 = vol[z1o + y0o + cx1];
        const float v011 = vol[z1o + y1o + cx0];
        const float v111 = vol[z1o + y1o + cx1];
        const float s0 = gy0 * fmaf(gx0, v000, gx1 * v100)
                       + gy1 * fmaf(gx0, v010, gx1 * v110);
        const float s1 = gy0 * fmaf(gx0, v001, gx1 * v101)
                       + gy1 * fmaf(gx0, v011, gx1 * v111);
        acc = fmaf(gz0, s0, fmaf(gz1, s1, acc));
    }

    out[(bq << 14) + p] = acc;
}

extern "C" void kernel_launch(void* const* d_in, const int* in_sizes, int n_in,
                              void* d_out, int out_size, void* d_ws, size_t ws_size,
                              hipStream_t stream) {
    const float* density  = (const float*)d_in[0];
    const float* rotation = (const float*)d_in[1];
    float* out = (float*)d_out;

    if (ws_size >= PACKED_BYTES) {
        uint2* packed = (uint2*)d_ws;
        pack_kernel<<<8192, 256, 0, stream>>>(density, packed);
        proj_kernel_packed<<<4096, 128, 0, stream>>>(packed, rotation, out);
    } else {
        proj_kernel_fallback<<<2048, 256, 0, stream>>>(density, rotation, out);
    }
}

// Round 11
// 216.031 us; speedup vs baseline: 1.2436x; 1.2436x over previous
//
#include <hip/hip_runtime.h>

// SpatialGridProjector: out[b,q,j,i] = sum_k trilinear(density[b], P(i,j,k))
// X(k) = Ax + k*R20, Y(k) = Ay + k*R21, Z(k) = Az + k*R22  (voxel coords)
// grid_sample(align_corners=True, zero padding).
//
// R10 = exact R6 structure (best measured: 2048 blocks x 256 thr, wave=64x1
// row, direct store) + 6-stage interior pipeline WITHOUT a min-waves bound.
// R9's 6-stage attempt regressed only because __launch_bounds__(128,8)
// capped VGPRs -> scratch spill (WRITE_SIZE 2->173 MB). Here VGPR is free
// (<=64 expected), so the deeper MLP gets a clean test.

#define LSZ 128
#define PACKED_BYTES ((size_t)4 * 128 * 128 * 128 * 8)  // 64 MiB

typedef unsigned int u4v __attribute__((ext_vector_type(4), aligned(8)));

__device__ __forceinline__ float bl(unsigned int d) {
    return __uint_as_float(d << 16);
}
__device__ __forceinline__ float bh(unsigned int d) {
    return __uint_as_float(d & 0xffff0000u);
}
__device__ __forceinline__ unsigned int pk2(float lo, float hi) {
    unsigned int ul = __float_as_uint(lo), uh = __float_as_uint(hi);
    ul = (ul + 0x7fffu + ((ul >> 16) & 1u)) >> 16;   // RNE bf16
    uh = (uh + 0x7fffu + ((uh >> 16) & 1u)) >> 16;
    return ul | (uh << 16);
}

// ---------------- pack kernel: f32 volume -> corner-packed bf16 -------------
// entry (z,y,x): dword0 = bf16{ v(z,y,x), v(z,y+1,x) }
//                dword1 = bf16{ v(z+1,y,x), v(z+1,y+1,x) }
__global__ __launch_bounds__(256) void pack_kernel(
    const float* __restrict__ density, uint2* __restrict__ packed)
{
    const int xcd = blockIdx.x & 7;
    const int g   = blockIdx.x >> 3;          // 0..1023
    const int b   = g >> 8;                   // 0..3
    const int rem = g & 255;
    const int zl  = rem >> 4;                 // 0..15
    const int yo  = rem & 15;                 // 0..15
    const int z   = (xcd << 4) + zl;          // 0..127
    const int y   = (yo << 3) + (threadIdx.x >> 5);
    const int xq  = (threadIdx.x & 31) << 2;

    const float* __restrict__ v = density + ((size_t)b << 21);
    const int y1 = min(y + 1, 127), z1 = min(z + 1, 127);
    const float4 a0 = *(const float4*)(v + (z  << 14) + (y  << 7) + xq);
    const float4 a1 = *(const float4*)(v + (z  << 14) + (y1 << 7) + xq);
    const float4 c0 = *(const float4*)(v + (z1 << 14) + (y  << 7) + xq);
    const float4 c1 = *(const float4*)(v + (z1 << 14) + (y1 << 7) + xq);
    uint4 o0, o1;
    o0.x = pk2(a0.x, a1.x); o0.y = pk2(c0.x, c1.x);
    o0.z = pk2(a0.y, a1.y); o0.w = pk2(c0.y, c1.y);
    o1.x = pk2(a0.z, a1.z); o1.y = pk2(c0.z, c1.z);
    o1.z = pk2(a0.w, a1.w); o1.w = pk2(c0.w, c1.w);
    uint4* dst = (uint4*)(packed + ((size_t)b << 21) + (z << 14) + (y << 7) + xq);
    dst[0] = o0; dst[1] = o1;
}

// ---------------- interior fast path (all corners valid) --------------------
#define FPREPI(S, kk) do {                                                    \
    const float kf_ = (float)min((kk), d);                                    \
    const float X_ = fmaf(kf_, R20, Ax);                                      \
    const float Y_ = fmaf(kf_, R21, Ay);                                      \
    const float Z_ = fmaf(kf_, R22, Az);                                      \
    const int ix_ = (int)X_;                                                  \
    const int iy_ = (int)Y_;                                                  \
    const int iz_ = (int)Z_;                                                  \
    fx##S = X_ - (float)ix_;                                                  \
    fy##S = Y_ - (float)iy_;                                                  \
    fz##S = Z_ - (float)iz_;                                                  \
    u##S = *(const u4v*)(vol2 + ((iz_ << 14) + (iy_ << 7) + ix_));            \
} while (0)

#define FCONSI(S) do {                                                        \
    const float gx0 = 1.0f - fx##S;                                           \
    const float gy0 = 1.0f - fy##S;                                           \
    const float gz0 = 1.0f - fz##S;                                           \
    const float c000 = bl(u##S.x), c010 = bh(u##S.x);                         \
    const float c001 = bl(u##S.y), c011 = bh(u##S.y);                         \
    const float c100 = bl(u##S.z), c110 = bh(u##S.z);                         \
    const float c101 = bl(u##S.w), c111 = bh(u##S.w);                         \
    const float s0_ = gy0   * fmaf(gx0, c000, fx##S * c100)                   \
                    + fy##S * fmaf(gx0, c010, fx##S * c110);                  \
    const float s1_ = gy0   * fmaf(gx0, c001, fx##S * c101)                   \
                    + fy##S * fmaf(gx0, c011, fx##S * c111);                  \
    acc = fmaf(gz0, s0_, fmaf(fz##S, s1_, acc));                              \
} while (0)

// ---------------- boundary safe path (clamped + per-corner selects) ---------
#define SPREP(S, kk) do {                                                     \
    const float kf_ = (float)(kk);                                            \
    const float X_ = fmaf(kf_, R20, Ax);                                      \
    const float Y_ = fmaf(kf_, R21, Ay);                                      \
    const float Z_ = fmaf(kf_, R22, Az);                                      \
    const int ix_ = (int)floorf(X_);                                          \
    const int iy_ = (int)floorf(Y_);                                          \
    const int iz_ = (int)floorf(Z_);                                          \
    const int ex_ = min(max(ix_, 0), 126);                                    \
    const int ey_ = min(max(iy_, 0), 126);                                    \
    const int ez_ = min(max(iz_, 0), 126);                                    \
    u##S = *(const u4v*)(vol2 + ((ez_ << 14) + (ey_ << 7) + ex_));            \
} while (0)

#define SCONS(S, kk) do {                                                     \
    const float kf_ = (float)(kk);                                            \
    const float X_ = fmaf(kf_, R20, Ax);                                      \
    const float Y_ = fmaf(kf_, R21, Ay);                                      \
    const float Z_ = fmaf(kf_, R22, Az);                                      \
    const float xf_ = floorf(X_), yf_ = floorf(Y_), zf_ = floorf(Z_);         \
    const int ix_ = (int)xf_, iy_ = (int)yf_, iz_ = (int)zf_;                 \
    const float fx_ = X_ - xf_, fy_ = Y_ - yf_, fz_ = Z_ - zf_;               \
    const bool vx0_ = (ix_ >= 0)  & (ix_ <= 127);                             \
    const bool vx1_ = (ix_ >= -1) & (ix_ <= 126);                             \
    const bool vy0_ = (iy_ >= 0)  & (iy_ <= 127);                             \
    const bool vy1_ = (iy_ >= -1) & (iy_ <= 126);                             \
    const bool vz0_ = (iz_ >= 0)  & (iz_ <= 127);                             \
    const bool vz1_ = (iz_ >= -1) & (iz_ <= 126);                             \
    const float gx0 = vx0_ ? (1.0f - fx_) : 0.0f;                             \
    const float gx1 = vx1_ ? fx_ : 0.0f;                                      \
    const float gy0 = vy0_ ? (1.0f - fy_) : 0.0f;                             \
    const float gy1 = vy1_ ? fy_ : 0.0f;                                      \
    const float gz0 = vz0_ ? (1.0f - fz_) : 0.0f;                             \
    const float gz1 = vz1_ ? fz_ : 0.0f;                                      \
    const bool xhi_ = (ix_ > 126), xlo_ = (ix_ < 0);                          \
    const bool yhi_ = (iy_ > 126), ylo_ = (iy_ < 0);                          \
    const bool zhi_ = (iz_ > 126), zlo_ = (iz_ < 0);                          \
    const unsigned int a0z0 = xhi_ ? u##S.z : u##S.x;                         \
    const unsigned int a0z1 = xhi_ ? u##S.w : u##S.y;                         \
    const unsigned int a1z0 = xlo_ ? u##S.x : u##S.z;                         \
    const unsigned int a1z1 = xlo_ ? u##S.y : u##S.w;                         \
    const unsigned int dA = zhi_ ? a0z1 : a0z0;                               \
    const unsigned int dB = zlo_ ? a0z0 : a0z1;                               \
    const unsigned int dC = zhi_ ? a1z1 : a1z0;                               \
    const unsigned int dD = zlo_ ? a1z0 : a1z1;                               \
    const float c000 = yhi_ ? bh(dA) : bl(dA);                                \
    const float c010 = ylo_ ? bl(dA) : bh(dA);                                \
    const float c100 = yhi_ ? bh(dC) : bl(dC);                                \
    const float c110 = ylo_ ? bl(dC) : bh(dC);                                \
    const float c001 = yhi_ ? bh(dB) : bl(dB);                                \
    const float c011 = ylo_ ? bl(dB) : bh(dB);                                \
    const float c101 = yhi_ ? bh(dD) : bl(dD);                                \
    const float c111 = ylo_ ? bl(dD) : bh(dD);                                \
    const float s0_ = gy0 * fmaf(gx0, c000, gx1 * c100)                       \
                    + gy1 * fmaf(gx0, c010, gx1 * c110);                      \
    const float s1_ = gy0 * fmaf(gx0, c001, gx1 * c101)                       \
                    + gy1 * fmaf(gx0, c011, gx1 * c111);                      \
    acc = fmaf(gz0, s0_, fmaf(gz1, s1_, acc));                                \
} while (0)

__global__ __launch_bounds__(256) void proj_kernel_packed(
    const uint2* __restrict__ packed,    // (B, L, L, L) corner-packed bf16
    const float* __restrict__ rotation,  // (B, Q, 3, 3)
    float* __restrict__ out)             // (B, Q, L, L)
{
    // XCD swizzle: volume b -> XCDs {2b, 2b+1} (R6 mapping, best measured).
    const int xcd  = blockIdx.x & 7;
    const int slot = blockIdx.x >> 3;          // 0..255
    const int b    = xcd >> 1;
    const int tile = ((xcd & 1) << 8) + slot;  // 0..511
    const int q    = tile >> 6;                // 0..7
    const int blk  = tile & 63;
    const int bq   = (b << 3) + q;

    const int p = (blk << 8) + threadIdx.x;    // pixel in image, 0..16383
    const int i = p & (LSZ - 1);
    const int j = p >> 7;

    const float* R = rotation + bq * 9;
    const float R00 = R[0], R01 = R[1], R02 = R[2];
    const float R10 = R[3], R11 = R[4], R12 = R[5];
    const float R20 = R[6], R21 = R[7], R22 = R[8];

    const float step = 2.0f / 127.0f;
    const float li = -1.0f + (float)i * step;
    const float lj = -1.0f + (float)j * step;

    const float Ax = 63.5f * (li * R00 + lj * R10 - R20 + 1.0f);
    const float Ay = 63.5f * (li * R01 + lj * R11 - R21 + 1.0f);
    const float Az = 63.5f * (li * R02 + lj * R12 - R22 + 1.0f);

    // outer interval: A + k*s in (-1, 128); interior: in [0, 126.95]
    float klo = 0.0f, khi = 127.0f;
    float klo2 = 0.0f, khi2 = 127.0f;
    bool empty = false, empty2 = false;
    {
        const float a_[3] = {Ax, Ay, Az};
        const float s_[3] = {R20, R21, R22};
        #pragma unroll
        for (int m = 0; m < 3; ++m) {
            if (fabsf(s_[m]) > 1e-6f) {
                const float r = 1.0f / s_[m];
                const float t0 = (-1.0f   - a_[m]) * r;
                const float t1 = (128.0f  - a_[m]) * r;
                klo = fmaxf(klo, fminf(t0, t1));
                khi = fminf(khi, fmaxf(t0, t1));
                const float w0 = (0.0f    - a_[m]) * r;
                const float w1 = (126.95f - a_[m]) * r;
                klo2 = fmaxf(klo2, fminf(w0, w1));
                khi2 = fminf(khi2, fmaxf(w0, w1));
            } else {
                if (a_[m] <= -1.0f   || a_[m] >= 128.0f)   empty  = true;
                if (a_[m] <  0.001f  || a_[m] >  126.94f)  empty2 = true;
            }
        }
    }
    int a   = (int)ceilf(klo - 1e-3f);
    int bnd = (int)floorf(khi + 1e-3f);
    if (a < 0) a = 0;
    if (bnd > 127) bnd = 127;
    if (empty) bnd = a - 1;

    int c = (int)ceilf(klo2 + 0.05f);
    int d = (int)floorf(khi2 - 0.05f);
    if (c < a) c = a;
    if (d > bnd) d = bnd;
    if (empty2 || d < c) { c = bnd + 1; d = bnd; }

    const uint2* __restrict__ vol2 = packed + ((size_t)b << 21);

    float acc = 0.0f;
    u4v uA, uB, uC, uD, uE, uF;
    float fxA, fyA, fzA, fxB, fyB, fzB, fxC, fyC, fzC;
    float fxD, fyD, fzD, fxE, fyE, fzE, fxF, fyF, fzF;

    // ---- boundary head: [a, c-1] ----
    {
        int k = a;
        const int e = c - 1;
        if (k <= e) {
            SPREP(A, k);
            while (k <= e) {
                const int kn = k + 1;
                const bool hasB = (kn <= e);
                if (hasB) SPREP(B, kn);
                SCONS(A, k);
                if (hasB) SCONS(B, kn);
                k += 2;
                if (k <= e) SPREP(A, k);
            }
        }
    }

    // ---- interior: [c, d], 6-stage fast pipeline (no clamps/selects) ----
    {
        int n = d - c + 1;
        int k = c;
        if (n > 0) {
            FPREPI(A, k);     FPREPI(B, k + 1); FPREPI(C, k + 2);
            FPREPI(D, k + 3); FPREPI(E, k + 4);
            while (n > 0) {
                FPREPI(F, k + 5);
                FCONSI(A);
                FPREPI(A, k + 6);
                if (n > 1) FCONSI(B);
                FPREPI(B, k + 7);
                if (n > 2) FCONSI(C);
                FPREPI(C, k + 8);
                if (n > 3) FCONSI(D);
                FPREPI(D, k + 9);
                if (n > 4) FCONSI(E);
                FPREPI(E, k + 10);
                if (n > 5) FCONSI(F);
                k += 6; n -= 6;
            }
        }
    }

    // ---- boundary tail: [d+1, bnd] ----
    {
        int k = d + 1;
        const int e = bnd;
        if (k <= e) {
            SPREP(A, k);
            while (k <= e) {
                const int kn = k + 1;
                const bool hasB = (kn <= e);
                if (hasB) SPREP(B, kn);
                SCONS(A, k);
                if (hasB) SCONS(B, kn);
                k += 2;
                if (k <= e) SPREP(A, k);
            }
        }
    }

    out[(bq << 14) + p] = acc;
}

// ---------------- fallback (f32 direct) if ws too small ---------------------
__global__ __launch_bounds__(256) void proj_kernel_fallback(
    const float* __restrict__ density,
    const float* __restrict__ rotation,
    float* __restrict__ out)
{
    const int xcd  = blockIdx.x & 7;
    const int slot = blockIdx.x >> 3;
    const int b    = xcd >> 1;
    const int tile = ((xcd & 1) << 8) + slot;
    const int q    = tile >> 6;
    const int blk  = tile & 63;
    const int bq   = (b << 3) + q;

    const int p = (blk << 8) + threadIdx.x;
    const int i = p & (LSZ - 1);
    const int j = p >> 7;

    const float* R = rotation + bq * 9;
    const float R00 = R[0], R01 = R[1], R02 = R[2];
    const float R10 = R[3], R11 = R[4], R12 = R[5];
    const float R20 = R[6], R21 = R[7], R22 = R[8];

    const float step = 2.0f / 127.0f;
    const float li = -1.0f + (float)i * step;
    const float lj = -1.0f + (float)j * step;

    const float Ax = 63.5f * (li * R00 + lj * R10 - R20 + 1.0f);
    const float Ay = 63.5f * (li * R01 + lj * R11 - R21 + 1.0f);
    const float Az = 63.5f * (li * R02 + lj * R12 - R22 + 1.0f);

    float klo = 0.0f, khi = 127.0f;
    bool empty = false;
    {
        const float a_[3] = {Ax, Ay, Az};
        const float s_[3] = {R20, R21, R22};
        #pragma unroll
        for (int m = 0; m < 3; ++m) {
            if (fabsf(s_[m]) > 1e-6f) {
                const float t0 = (-1.0f  - a_[m]) / s_[m];
                const float t1 = (128.0f - a_[m]) / s_[m];
                klo = fmaxf(klo, fminf(t0, t1));
                khi = fminf(khi, fmaxf(t0, t1));
            } else if (a_[m] <= -1.0f || a_[m] >= 128.0f) {
                empty = true;
            }
        }
    }
    int k_start = (int)ceilf(klo - 1e-3f);
    int k_end   = (int)floorf(khi + 1e-3f);
    if (k_start < 0) k_start = 0;
    if (k_end > 127) k_end = 127;
    if (empty) k_end = k_start - 1;

    const float* __restrict__ vol = density + (size_t)b * (LSZ * LSZ * LSZ);

    float acc = 0.0f;
    for (int k = k_start; k <= k_end; ++k) {
        const float kf = (float)k;
        const float X = fmaf(kf, R20, Ax);
        const float Y = fmaf(kf, R21, Ay);
        const float Z = fmaf(kf, R22, Az);
        const float xf = floorf(X), yf = floorf(Y), zf = floorf(Z);
        const int ix = (int)xf, iy = (int)yf, iz = (int)zf;
        const float fx = X - xf, fy = Y - yf, fz = Z - zf;
        const bool vx0 = (ix >= 0)  & (ix <= 127);
        const bool vx1 = (ix >= -1) & (ix <= 126);
        const bool vy0 = (iy >= 0)  & (iy <= 127);
        const bool vy1 = (iy >= -1) & (iy <= 126);
        const bool vz0 = (iz >= 0)  & (iz <= 127);
        const bool vz1 = (iz >= -1) & (iz <= 126);
        const int cx0 = min(max(ix, 0), 127);
        const int cx1 = min(max(ix + 1, 0), 127);
        const int cy0 = min(max(iy, 0), 127);
        const int cy1 = min(max(iy + 1, 0), 127);
        const int cz0 = min(max(iz, 0), 127);
        const int cz1 = min(max(iz + 1, 0), 127);
        const float gx0 = vx0 ? (1.0f - fx) : 0.0f;
        const float gx1 = vx1 ? fx : 0.0f;
        const float gy0 = vy0 ? (1.0f - fy) : 0.0f;
        const float gy1 = vy1 ? fy : 0.0f;
        const float gz0 = vz0 ? (1.0f - fz) : 0.0f;
        const float gz1 = vz1 ? fz : 0.0f;
        const int z0o = cz0 << 14, z1o = cz1 << 14;
        const int y0o = cy0 << 7,  y1o = cy1 << 7;
        const float v000 = vol[z0o + y0o + cx0];
        const float v100 = vol[z0o + y0o + cx1];
        const float v010 = vol[z0o + y1o + cx0];
        const float v110 = vol[z0o + y1o + cx1];
        const float v001 = vol[z1o + y0o + cx0];
        const float v101 = vol[z1o + y0o + cx1];
        const float v011 = vol[z1o + y1o + cx0];
        const float v111 = vol[z1o + y1o + cx1];
        const float s0 = gy0 * fmaf(gx0, v000, gx1 * v100)
                       + gy1 * fmaf(gx0, v010, gx1 * v110);
        const float s1 = gy0 * fmaf(gx0, v001, gx1 * v101)
                       + gy1 * fmaf(gx0, v011, gx1 * v111);
        acc = fmaf(gz0, s0, fmaf(gz1, s1, acc));
    }

    out[(bq << 14) + p] = acc;
}

extern "C" void kernel_launch(void* const* d_in, const int* in_sizes, int n_in,
                              void* d_out, int out_size, void* d_ws, size_t ws_size,
                              hipStream_t stream) {
    const float* density  = (const float*)d_in[0];
    const float* rotation = (const float*)d_in[1];
    float* out = (float*)d_out;

    if (ws_size >= PACKED_BYTES) {
        uint2* packed = (uint2*)d_ws;
        pack_kernel<<<8192, 256, 0, stream>>>(density, packed);
        proj_kernel_packed<<<2048, 256, 0, stream>>>(packed, rotation, out);
    } else {
        proj_kernel_fallback<<<2048, 256, 0, stream>>>(density, rotation, out);
    }
}